// Round 2
// baseline (2399.120 us; speedup 1.0000x reference)
//
#include <hip/hip_runtime.h>
#include <hip/hip_bf16.h>
#include <math.h>
#include <stdint.h>

typedef __bf16 bf16_t;
typedef __bf16 bf16x8 __attribute__((ext_vector_type(8)));
typedef __bf16 bf16x4v __attribute__((ext_vector_type(4)));
typedef float f32x4 __attribute__((ext_vector_type(4)));

#define BB 4
#define SS 2048
#define DD 1024
#define HH 16
#define SCALE 0.125f   // 1/sqrt(64)
static const size_t NE = (size_t)BB * SS * DD;   // 8388608

// ---------------- dtype-generic load/store helpers ----------------
__device__ inline bf16x8 load8(const bf16_t* p) { return *(const bf16x8*)p; }
__device__ inline bf16x8 load8(const float* p) {
    f32x4 a = *(const f32x4*)p;
    f32x4 b = *(const f32x4*)(p + 4);
    bf16x8 r;
    for (int i = 0; i < 4; ++i) { r[i] = (bf16_t)a[i]; r[4 + i] = (bf16_t)b[i]; }
    return r;
}
__device__ inline f32x4 load4f(const bf16_t* p) {
    bf16x4v v = *(const bf16x4v*)p;
    return (f32x4){(float)v[0], (float)v[1], (float)v[2], (float)v[3]};
}
__device__ inline f32x4 load4f(const float* p) { return *(const f32x4*)p; }
__device__ inline void store4(bf16_t* p, f32x4 v) {
    bf16x4v o;
    for (int j = 0; j < 4; ++j) o[j] = (bf16_t)v[j];
    *(bf16x4v*)p = o;
}
__device__ inline void store4(float* p, f32x4 v) { *(f32x4*)p = v; }
__device__ inline void store16(bf16_t* p, const bf16_t* s) {
    *(bf16x8*)p       = *(const bf16x8*)s;
    *(bf16x8*)(p + 8) = *(const bf16x8*)(s + 8);
}
__device__ inline void store16(float* p, const bf16_t* s) {
    for (int j = 0; j < 16; j += 4) {
        f32x4 v = {(float)s[j], (float)s[j + 1], (float)s[j + 2], (float)s[j + 3]};
        *(f32x4*)(p + j) = v;
    }
}

// ---------------------------------------------------------------------------
// Probe: flags[0] = input float dtype (0=bf16, 1=fp32)
//        flags[1] = mask layout (0=byte, 1=int32, 2=int64)
// fp32 buffer read as bf16: even elements are float mantissa bytes -> ~37%
// have |x|>1e10 or NaN. Genuine bf16 N(0,1) data never does.
// ---------------------------------------------------------------------------
__global__ void probe_kernel(const uint16_t* __restrict__ q,
                             const uint8_t* __restrict__ m,
                             int* __restrict__ flags)
{
    __shared__ int s_f32, s_byte, s_i32;
    if (threadIdx.x == 0) { s_f32 = 0; s_byte = 0; s_i32 = 0; }
    __syncthreads();
    {
        unsigned bits = ((unsigned)q[threadIdx.x]) << 16;
        float f = __uint_as_float(bits);
        if (!(fabsf(f) < 1e10f)) atomicOr(&s_f32, 1);
    }
    for (int j = threadIdx.x; j < 4096; j += 256) {
        if (m[j]) {
            if (j & 3) atomicOr(&s_byte, 1);
            else if ((j & 7) == 4) atomicOr(&s_i32, 1);
        }
    }
    __syncthreads();
    if (threadIdx.x == 0) {
        flags[0] = s_f32 ? 1 : 0;
        flags[1] = s_byte ? 0 : (s_i32 ? 1 : 2);
    }
}

// ---------------------------------------------------------------------------
// Y = X * W^T + bias  (TX/TW in, bf16 out, fp32 MFMA accumulate)
// 128x128 tile, BK=32, 4 waves (2x2), each wave 64x64 (4x4 16x16 frags)
// ---------------------------------------------------------------------------
template<typename TX, typename TW>
__global__ __launch_bounds__(256) void gemm_bt_bias(
    const TX* __restrict__ X, const TW* __restrict__ W,
    const TW* __restrict__ bias, bf16_t* __restrict__ Y,
    int M, int N, int K, const int* __restrict__ flags, int want)
{
    if (flags[0] != want) return;

    __shared__ __align__(16) bf16_t As[128][40];
    __shared__ __align__(16) bf16_t Bs[128][40];

    const int tid = threadIdx.x;
    const int wave = tid >> 6;
    const int lane = tid & 63;
    const int quad = lane >> 4;
    const int l15  = lane & 15;
    const int wm = wave >> 1, wn = wave & 1;

    const int m0 = blockIdx.y * 128;
    const int n0 = blockIdx.x * 128;

    f32x4 acc[4][4];
    for (int i = 0; i < 4; ++i)
        for (int j = 0; j < 4; ++j)
            acc[i][j] = (f32x4){0.f, 0.f, 0.f, 0.f};

    for (int k0 = 0; k0 < K; k0 += 32) {
        __syncthreads();
        for (int j = 0; j < 2; ++j) {
            int c = tid * 2 + j;
            int row = c >> 2;
            int cc  = (c & 3) * 8;
            *(bf16x8*)&As[row][cc] = load8(&X[(size_t)(m0 + row) * K + k0 + cc]);
            *(bf16x8*)&Bs[row][cc] = load8(&W[(size_t)(n0 + row) * K + k0 + cc]);
        }
        __syncthreads();
        bf16x8 a[4], b[4];
        for (int mt = 0; mt < 4; ++mt)
            a[mt] = *(const bf16x8*)&As[wm * 64 + mt * 16 + l15][quad * 8];
        for (int nt = 0; nt < 4; ++nt)
            b[nt] = *(const bf16x8*)&Bs[wn * 64 + nt * 16 + l15][quad * 8];
        for (int mt = 0; mt < 4; ++mt)
            for (int nt = 0; nt < 4; ++nt)
                acc[mt][nt] = __builtin_amdgcn_mfma_f32_16x16x32_bf16(a[mt], b[nt], acc[mt][nt], 0, 0, 0);
    }

    for (int nt = 0; nt < 4; ++nt) {
        int n = n0 + wn * 64 + nt * 16 + l15;
        float bv = (float)bias[n];
        for (int mt = 0; mt < 4; ++mt) {
            int mbase = m0 + wm * 64 + mt * 16 + quad * 4;
            for (int r = 0; r < 4; ++r)
                Y[(size_t)(mbase + r) * N + n] = (bf16_t)(acc[mt][nt][r] + bv);
        }
    }
}

// ---------------------------------------------------------------------------
// Fused attention: per (b,h,64-row q-tile). Two-pass softmax.
// ---------------------------------------------------------------------------
template<typename T>
__global__ __launch_bounds__(256) void attn_fused(
    const bf16_t* Qp, const bf16_t* Kp, const bf16_t* Vp,
    const void* maskp, const int* __restrict__ flags, int want,
    T* attn_out, bf16_t* ctx_out)
{
    if (flags[0] != want) return;

    __shared__ __align__(16) bf16_t Qs[64][72];
    __shared__ __align__(16) bf16_t Ks[64][72];
    __shared__ __align__(16) bf16_t Ps[64][72];
    __shared__ __align__(16) bf16_t VTs[64][72];

    const int tid  = threadIdx.x;
    const int wave = tid >> 6;
    const int lane = tid & 63;
    const int quad = lane >> 4;
    const int l15  = lane & 15;
    const int qt = blockIdx.x;
    const int bh = blockIdx.y;
    const int b  = bh / HH;
    const int h  = bh % HH;
    const int q0 = qt * 64;

    const int mmode = flags[1];
    const uint8_t* m8  = (const uint8_t*)maskp;
    const int*     m32 = (const int*)maskp;
    const size_t mbase = (size_t)b * SS * SS;
    const int qrow_base = q0 + wave * 16 + quad * 4;

    for (int j = 0; j < 2; ++j) {
        int c = tid * 2 + j;
        int row = c >> 3, cc = (c & 7) * 8;
        *(bf16x8*)&Qs[row][cc] =
            *(const bf16x8*)&Qp[(size_t)(b * SS + q0 + row) * DD + h * 64 + cc];
    }

    float mrow[4], lrow[4];
    for (int r = 0; r < 4; ++r) { mrow[r] = -INFINITY; lrow[r] = 0.f; }

    // ---------------- PASS 1 ----------------
    for (int kt = 0; kt < 32; ++kt) {
        __syncthreads();
        for (int j = 0; j < 2; ++j) {
            int c = tid * 2 + j;
            int row = c >> 3, cc = (c & 7) * 8;
            *(bf16x8*)&Ks[row][cc] =
                *(const bf16x8*)&Kp[(size_t)(b * SS + kt * 64 + row) * DD + h * 64 + cc];
        }
        __syncthreads();
        bf16x8 aq0 = *(const bf16x8*)&Qs[wave * 16 + l15][quad * 8];
        bf16x8 aq1 = *(const bf16x8*)&Qs[wave * 16 + l15][32 + quad * 8];
        float sv[4][4];
        for (int nt = 0; nt < 4; ++nt) {
            bf16x8 b0 = *(const bf16x8*)&Ks[nt * 16 + l15][quad * 8];
            bf16x8 b1 = *(const bf16x8*)&Ks[nt * 16 + l15][32 + quad * 8];
            f32x4 s = (f32x4){0.f, 0.f, 0.f, 0.f};
            s = __builtin_amdgcn_mfma_f32_16x16x32_bf16(aq0, b0, s, 0, 0, 0);
            s = __builtin_amdgcn_mfma_f32_16x16x32_bf16(aq1, b1, s, 0, 0, 0);
            int kcol = kt * 64 + nt * 16 + l15;
            for (int r = 0; r < 4; ++r) {
                size_t mi = mbase + (size_t)(qrow_base + r) * SS + kcol;
                bool msk = (mmode == 0) ? (m8[mi] != 0)
                         : (mmode == 1) ? (m32[mi] != 0)
                                        : (m32[2 * mi] != 0);
                sv[nt][r] = msk ? -INFINITY : s[r] * SCALE;
            }
        }
        for (int r = 0; r < 4; ++r) {
            float mx = fmaxf(fmaxf(sv[0][r], sv[1][r]), fmaxf(sv[2][r], sv[3][r]));
            for (int off = 1; off < 16; off <<= 1) mx = fmaxf(mx, __shfl_xor(mx, off));
            float mnew = fmaxf(mrow[r], mx);
            float ps = 0.f;
            for (int nt = 0; nt < 4; ++nt)
                ps += (sv[nt][r] == -INFINITY) ? 0.f : __expf(sv[nt][r] - mnew);
            for (int off = 1; off < 16; off <<= 1) ps += __shfl_xor(ps, off);
            float alpha = (mrow[r] == mnew) ? 1.f : __expf(mrow[r] - mnew);
            lrow[r] = lrow[r] * alpha + ps;
            mrow[r] = mnew;
        }
    }

    float rinv[4];
    for (int r = 0; r < 4; ++r) rinv[r] = (lrow[r] > 0.f) ? 1.f / lrow[r] : 0.f;

    f32x4 cacc[4];
    for (int dt = 0; dt < 4; ++dt) cacc[dt] = (f32x4){0.f, 0.f, 0.f, 0.f};

    // ---------------- PASS 2 ----------------
    for (int kt = 0; kt < 32; ++kt) {
        __syncthreads();
        for (int j = 0; j < 2; ++j) {
            int c = tid * 2 + j;
            int row = c >> 3, cc = (c & 7) * 8;
            *(bf16x8*)&Ks[row][cc] =
                *(const bf16x8*)&Kp[(size_t)(b * SS + kt * 64 + row) * DD + h * 64 + cc];
        }
        {   // stage V transposed: VTs[d][k]
            int k = tid >> 2;
            int dch = (tid & 3) * 16;
            const bf16_t* vsrc = &Vp[(size_t)(b * SS + kt * 64 + k) * DD + h * 64 + dch];
            bf16x8 v0 = *(const bf16x8*)vsrc;
            bf16x8 v1 = *(const bf16x8*)(vsrc + 8);
            for (int j = 0; j < 8; ++j) VTs[dch + j][k] = v0[j];
            for (int j = 0; j < 8; ++j) VTs[dch + 8 + j][k] = v1[j];
        }
        __syncthreads();
        bf16x8 aq0 = *(const bf16x8*)&Qs[wave * 16 + l15][quad * 8];
        bf16x8 aq1 = *(const bf16x8*)&Qs[wave * 16 + l15][32 + quad * 8];
        for (int nt = 0; nt < 4; ++nt) {
            bf16x8 b0 = *(const bf16x8*)&Ks[nt * 16 + l15][quad * 8];
            bf16x8 b1 = *(const bf16x8*)&Ks[nt * 16 + l15][32 + quad * 8];
            f32x4 s = (f32x4){0.f, 0.f, 0.f, 0.f};
            s = __builtin_amdgcn_mfma_f32_16x16x32_bf16(aq0, b0, s, 0, 0, 0);
            s = __builtin_amdgcn_mfma_f32_16x16x32_bf16(aq1, b1, s, 0, 0, 0);
            int kcol = kt * 64 + nt * 16 + l15;
            for (int r = 0; r < 4; ++r) {
                size_t mi = mbase + (size_t)(qrow_base + r) * SS + kcol;
                bool msk = (mmode == 0) ? (m8[mi] != 0)
                         : (mmode == 1) ? (m32[mi] != 0)
                                        : (m32[2 * mi] != 0);
                float p = msk ? 0.f : __expf(s[r] * SCALE - mrow[r]) * rinv[r];
                Ps[wave * 16 + quad * 4 + r][nt * 16 + l15] = (bf16_t)p;
            }
        }
        __syncthreads();
        bf16x8 ap0 = *(const bf16x8*)&Ps[wave * 16 + l15][quad * 8];
        bf16x8 ap1 = *(const bf16x8*)&Ps[wave * 16 + l15][32 + quad * 8];
        for (int dt = 0; dt < 4; ++dt) {
            bf16x8 bv0 = *(const bf16x8*)&VTs[dt * 16 + l15][quad * 8];
            bf16x8 bv1 = *(const bf16x8*)&VTs[dt * 16 + l15][32 + quad * 8];
            cacc[dt] = __builtin_amdgcn_mfma_f32_16x16x32_bf16(ap0, bv0, cacc[dt], 0, 0, 0);
            cacc[dt] = __builtin_amdgcn_mfma_f32_16x16x32_bf16(ap1, bv1, cacc[dt], 0, 0, 0);
        }
        {   // coalesced attn store, head-major [(h*B+b)][q][k]
            int row = tid >> 2;
            int ch  = (tid & 3) * 16;
            size_t dst = ((size_t)(h * BB + b) * SS + (q0 + row)) * SS + kt * 64 + ch;
            store16(&attn_out[dst], &Ps[row][ch]);
        }
    }

    for (int dt = 0; dt < 4; ++dt)
        for (int r = 0; r < 4; ++r)
            ctx_out[(size_t)(b * SS + qrow_base + r) * DD + h * 64 + dt * 16 + l15] =
                (bf16_t)cacc[dt][r];
}

// ---------------------------------------------------------------------------
// out = LN(proj + query) * gamma + beta   (proj bf16 scratch, already has +bo)
// ---------------------------------------------------------------------------
template<typename T>
__global__ __launch_bounds__(256) void ln_kernel(
    const bf16_t* __restrict__ P, const T* __restrict__ Qr,
    const T* __restrict__ gamma, const T* __restrict__ beta,
    T* __restrict__ out, const int* __restrict__ flags, int want)
{
    if (flags[0] != want) return;
    const int row = blockIdx.x;
    const int tid = threadIdx.x;
    const size_t base = (size_t)row * DD + tid * 4;
    f32x4 pv = load4f(&P[base]);
    f32x4 qv = load4f(&Qr[base]);
    float x[4]; float s = 0.f, s2 = 0.f;
    for (int j = 0; j < 4; ++j) {
        x[j] = pv[j] + qv[j];
        s += x[j]; s2 += x[j] * x[j];
    }
    for (int off = 1; off < 64; off <<= 1) {
        s  += __shfl_xor(s, off);
        s2 += __shfl_xor(s2, off);
    }
    __shared__ float sh[8];
    const int wave = tid >> 6, lane = tid & 63;
    if (lane == 0) { sh[wave] = s; sh[4 + wave] = s2; }
    __syncthreads();
    s  = sh[0] + sh[1] + sh[2] + sh[3];
    s2 = sh[4] + sh[5] + sh[6] + sh[7];
    float mean = s * (1.0f / DD);
    float var  = s2 * (1.0f / DD) - mean * mean;
    float inv  = rsqrtf(var + 1e-5f);
    f32x4 g  = load4f(&gamma[tid * 4]);
    f32x4 bt = load4f(&beta[tid * 4]);
    f32x4 o;
    for (int j = 0; j < 4; ++j)
        o[j] = g[j] * (x[j] - mean) * inv + bt[j];
    store4(&out[base], o);
}

// ---------------------------------------------------------------------------
template<typename T>
static void run_chain(void* const* d_in, void* d_out, bf16_t* Qp, bf16_t* Kp, bf16_t* Vp,
                      int* flags, int want, hipStream_t stream)
{
    const T* query = (const T*)d_in[0];
    const T* key   = (const T*)d_in[1];
    const T* value = (const T*)d_in[2];
    const void* mask = d_in[3];
    const T* Wq = (const T*)d_in[4];
    const T* bq = (const T*)d_in[5];
    const T* Wk = (const T*)d_in[6];
    const T* bk = (const T*)d_in[7];
    const T* Wv = (const T*)d_in[8];
    const T* bv = (const T*)d_in[9];
    const T* Wo = (const T*)d_in[10];
    const T* bo = (const T*)d_in[11];
    const T* gamma = (const T*)d_in[12];
    const T* beta  = (const T*)d_in[13];

    T* out  = (T*)d_out;
    T* attn = out + NE;
    const int M = BB * SS;

    dim3 gg(DD / 128, M / 128);
    gemm_bt_bias<T, T><<<gg, 256, 0, stream>>>(query, Wq, bq, Qp, M, DD, DD, flags, want);
    gemm_bt_bias<T, T><<<gg, 256, 0, stream>>>(key,   Wk, bk, Kp, M, DD, DD, flags, want);
    gemm_bt_bias<T, T><<<gg, 256, 0, stream>>>(value, Wv, bv, Vp, M, DD, DD, flags, want);

    attn_fused<T><<<dim3(SS / 64, BB * HH), 256, 0, stream>>>(
        Qp, Kp, Vp, mask, flags, want, attn, Qp);

    gemm_bt_bias<bf16_t, T><<<gg, 256, 0, stream>>>(Qp, Wo, bo, Kp, M, DD, DD, flags, want);

    ln_kernel<T><<<M, 256, 0, stream>>>(Kp, query, gamma, beta, out, flags, want);
}

extern "C" void kernel_launch(void* const* d_in, const int* in_sizes, int n_in,
                              void* d_out, int out_size, void* d_ws, size_t ws_size,
                              hipStream_t stream)
{
    int* flags = (int*)d_ws;
    bf16_t* Qp = (bf16_t*)((char*)d_ws + 16);
    bf16_t* Kp = Qp + NE;
    // V scratch lives in the LN-output region of d_out (written last by ln_kernel),
    // keeping the d_ws requirement down to 32 MB + 16 B.
    bf16_t* Vp = (bf16_t*)d_out;

    probe_kernel<<<1, 256, 0, stream>>>((const uint16_t*)d_in[0],
                                        (const uint8_t*)d_in[3], flags);

    run_chain<bf16_t>(d_in, d_out, Qp, Kp, Vp, flags, 0, stream);
    run_chain<float >(d_in, d_out, Qp, Kp, Vp, flags, 1, stream);
}